// Round 1
// baseline (322.610 us; speedup 1.0000x reference)
//
#include <hip/hip_runtime.h>
#include <cstdint>
#include <cstddef>

#define B_ 2
#define S_ 4096
#define D_ 1024
#define H_ 16
#define HD_ 64
#define NB_ 64
#define W_ 8
#define M_ (B_*S_)   // 8192

typedef __bf16 bf16_t;
typedef __bf16 bf16x8 __attribute__((ext_vector_type(8)));
typedef float f32x4 __attribute__((ext_vector_type(4)));

#define GLOAD_LDS16(gp, lp) \
  __builtin_amdgcn_global_load_lds((__attribute__((address_space(1))) void*)(gp), \
                                   (__attribute__((address_space(3))) void*)(lp), 16, 0, 0)

// ---------------- fp32 -> bf16 cast (hidden states) ----------------
__global__ void cast_bf16_kernel(const float* __restrict__ x, bf16_t* __restrict__ y, int n4) {
  int i = blockIdx.x * 256 + threadIdx.x;
  if (i >= n4) return;
  float4 v = ((const float4*)x)[i];
  union { bf16_t b[4]; uint2 u; } cv;
  cv.b[0] = (bf16_t)v.x; cv.b[1] = (bf16_t)v.y; cv.b[2] = (bf16_t)v.z; cv.b[3] = (bf16_t)v.w;
  ((uint2*)y)[i] = cv.u;
}

// ---------------- weight transpose + cast: wT[n][k] = (bf16)w[k][n] ----------------
__global__ void transpose_cast_kernel(const float* __restrict__ w0, const float* __restrict__ w1,
                                      const float* __restrict__ w2, const float* __restrict__ w3,
                                      bf16_t* __restrict__ out) {
  const float* w = (blockIdx.z == 0) ? w0 : (blockIdx.z == 1) ? w1 : (blockIdx.z == 2) ? w2 : w3;
  bf16_t* wt = out + (size_t)blockIdx.z * D_ * D_;
  __shared__ float tile[32][33];
  int x = blockIdx.x * 32 + threadIdx.x;
  int y0 = blockIdx.y * 32;
  for (int i = threadIdx.y; i < 32; i += 8)
    tile[i][threadIdx.x] = w[(size_t)(y0 + i) * D_ + x];
  __syncthreads();
  int x2 = blockIdx.y * 32 + threadIdx.x;   // k
  int y2 = blockIdx.x * 32;                 // n base
  for (int i = threadIdx.y; i < 32; i += 8)
    wt[(size_t)(y2 + i) * D_ + x2] = (bf16_t)tile[threadIdx.x][i];
}

// ---------------- GEMM: C[M,1024] = A[M,1024] @ Bt[n][k]^T ----------------
// 128x128 tile, BK=32, 4 waves each computing a 64x64 quadrant (4x4 of 16x16x32 mfma)
template<bool OBF>
__global__ __launch_bounds__(256) void gemm128(const bf16_t* __restrict__ A,
                                               const bf16_t* __restrict__ BtBase,
                                               void* __restrict__ Cbase) {
  const bf16_t* Bt = BtBase + (size_t)blockIdx.z * D_ * D_;
  const int mb = blockIdx.y * 128, nb = blockIdx.x * 128;
  const int tid = threadIdx.x;
  const int wid = tid >> 6, lane = tid & 63;
  const int quad = lane >> 4, l16 = lane & 15;
  const int wr = wid >> 1, wc = wid & 1;

  __shared__ bf16_t As[128 * 32];
  __shared__ bf16_t Bs[128 * 32];

  f32x4 acc[4][4];
#pragma unroll
  for (int mi = 0; mi < 4; ++mi)
#pragma unroll
    for (int ni = 0; ni < 4; ++ni)
      acc[mi][ni] = (f32x4){0.f, 0.f, 0.f, 0.f};

  // staging: 8 chunks of 1024B; wave w handles chunks w*2, w*2+1.
  // chunk ch covers rows [ch*16, ch*16+16), lane l -> row ch*16 + l/4, col (l&3)*8
  const int acol = (lane & 3) * 8;
  const int arow0 = wid * 32 + (lane >> 2);
  const bf16_t* gA = A + (size_t)(mb + arow0) * D_ + acol;
  const bf16_t* gB = Bt + (size_t)(nb + arow0) * D_ + acol;

  for (int kt = 0; kt < 32; ++kt) {
    const int k0 = kt * 32;
    __syncthreads();
#pragma unroll
    for (int c = 0; c < 2; ++c) {
      GLOAD_LDS16(gA + (size_t)c * 16 * D_ + k0, As + (wid * 2 + c) * 512);
      GLOAD_LDS16(gB + (size_t)c * 16 * D_ + k0, Bs + (wid * 2 + c) * 512);
    }
    __syncthreads();
    bf16x8 af[4], bfr[4];
#pragma unroll
    for (int mi = 0; mi < 4; ++mi)
      af[mi] = *(const bf16x8*)&As[(wr * 64 + mi * 16 + l16) * 32 + quad * 8];
#pragma unroll
    for (int ni = 0; ni < 4; ++ni)
      bfr[ni] = *(const bf16x8*)&Bs[(wc * 64 + ni * 16 + l16) * 32 + quad * 8];
#pragma unroll
    for (int mi = 0; mi < 4; ++mi)
#pragma unroll
      for (int ni = 0; ni < 4; ++ni)
        acc[mi][ni] = __builtin_amdgcn_mfma_f32_16x16x32_bf16(af[mi], bfr[ni], acc[mi][ni], 0, 0, 0);
  }

  // epilogue: C/D layout col=lane&15, row=quad*4+reg
  if constexpr (OBF) {
    bf16_t* Cp = (bf16_t*)Cbase + (size_t)blockIdx.z * M_ * D_;
#pragma unroll
    for (int mi = 0; mi < 4; ++mi)
#pragma unroll
      for (int ni = 0; ni < 4; ++ni)
#pragma unroll
        for (int r = 0; r < 4; ++r) {
          int row = mb + wr * 64 + mi * 16 + quad * 4 + r;
          int col = nb + wc * 64 + ni * 16 + l16;
          Cp[(size_t)row * D_ + col] = (bf16_t)acc[mi][ni][r];
        }
  } else {
    float* Cp = (float*)Cbase;
#pragma unroll
    for (int mi = 0; mi < 4; ++mi)
#pragma unroll
      for (int ni = 0; ni < 4; ++ni)
#pragma unroll
        for (int r = 0; r < 4; ++r) {
          int row = mb + wr * 64 + mi * 16 + quad * 4 + r;
          int col = nb + wc * 64 + ni * 16 + l16;
          Cp[(size_t)row * D_ + col] = acc[mi][ni][r];
        }
  }
}

// ---------------- RoPE (in-place on bf16 q,k) ----------------
__global__ void rope_kernel(bf16_t* __restrict__ q, bf16_t* __restrict__ k,
                            const int* __restrict__ pos_ids) {
  int idx = blockIdx.x * 256 + threadIdx.x;  // < M_*H_*32
  int j = idx & 31;
  int sh = idx >> 5;
  int h = sh & (H_ - 1);
  int bs = sh >> 4;  // b*S + s
  int pos = pos_ids[bs];
  // inv_freq = 10000^(-j/32) = exp2(-j * log2(10000)/32)
  float th = (float)pos * exp2f(-(float)j * 0.41524101186092034f);
  float sn, cs;
  sincosf(th, &sn, &cs);
  size_t base = (size_t)bs * D_ + h * HD_ + j;
  float x1 = (float)q[base], x2 = (float)q[base + 32];
  q[base]      = (bf16_t)(x1 * cs - x2 * sn);
  q[base + 32] = (bf16_t)(x2 * cs + x1 * sn);
  float y1 = (float)k[base], y2 = (float)k[base + 32];
  k[base]      = (bf16_t)(y1 * cs - y2 * sn);
  k[base + 32] = (bf16_t)(y2 * cs + y1 * sn);
}

// ---------------- block-sparse flash attention ----------------
// one workgroup per (qblock n, head h, batch b); 4 waves, each owns 16 query rows
__global__ __launch_bounds__(256) void attn_kernel(const bf16_t* __restrict__ q,
                                                   const bf16_t* __restrict__ k,
                                                   const bf16_t* __restrict__ v,
                                                   bf16_t* __restrict__ o) {
  const int n = blockIdx.x, h = blockIdx.y, b = blockIdx.z;
  const int tid = threadIdx.x;
  const int wid = tid >> 6, lane = tid & 63;
  const int quad = lane >> 4, l16 = lane & 15;

  __shared__ bf16_t Qs[64 * 64];
  __shared__ bf16_t Ks[64 * 64];
  __shared__ bf16_t Vt[64 * 64];      // transposed: Vt[hd][key]
  __shared__ bf16_t Ps[4][16 * 64];   // per-wave P tile

  const size_t rowbase = (size_t)(b * S_ + n * 64);
  const size_t hoff = (size_t)h * HD_;

#pragma unroll
  for (int it = 0; it < 2; ++it) {
    int e = (it * 256 + tid) * 8;
    int r = e >> 6, c = e & 63;
    *(uint4*)&Qs[e] = *(const uint4*)&q[(rowbase + r) * D_ + hoff + c];
  }

  f32x4 o_acc[4];
#pragma unroll
  for (int t = 0; t < 4; ++t) o_acc[t] = (f32x4){0.f, 0.f, 0.f, 0.f};
  float m_r[4] = {-1e30f, -1e30f, -1e30f, -1e30f};
  float l_r[4] = {0.f, 0.f, 0.f, 0.f};

  for (int wi = 0; wi < W_; ++wi) {
    const int kb = n - (W_ - 1) + wi;
    if (kb < 0) continue;  // uniform per block
    __syncthreads();       // prior iter's LDS reads done before overwrite
    const size_t krow = (size_t)(b * S_ + kb * 64);
#pragma unroll
    for (int it = 0; it < 2; ++it) {
      int e = (it * 256 + tid) * 8;
      int r = e >> 6, c = e & 63;
      *(uint4*)&Ks[e] = *(const uint4*)&k[(krow + r) * D_ + hoff + c];
      uint4 vv = *(const uint4*)&v[(krow + r) * D_ + hoff + c];
      const bf16_t* vp = (const bf16_t*)&vv;
#pragma unroll
      for (int j = 0; j < 8; ++j) Vt[(c + j) * 64 + r] = vp[j];
    }
    __syncthreads();

    // S = Q @ K^T  (per-wave 16x64)
    f32x4 sacc[4];
#pragma unroll
    for (int t = 0; t < 4; ++t) sacc[t] = (f32x4){0.f, 0.f, 0.f, 0.f};
    bf16x8 aq0 = *(const bf16x8*)&Qs[(wid * 16 + l16) * 64 + quad * 8];
    bf16x8 aq1 = *(const bf16x8*)&Qs[(wid * 16 + l16) * 64 + 32 + quad * 8];
#pragma unroll
    for (int t = 0; t < 4; ++t) {
      bf16x8 bk0 = *(const bf16x8*)&Ks[(t * 16 + l16) * 64 + quad * 8];
      bf16x8 bk1 = *(const bf16x8*)&Ks[(t * 16 + l16) * 64 + 32 + quad * 8];
      sacc[t] = __builtin_amdgcn_mfma_f32_16x16x32_bf16(aq0, bk0, sacc[t], 0, 0, 0);
      sacc[t] = __builtin_amdgcn_mfma_f32_16x16x32_bf16(aq1, bk1, sacc[t], 0, 0, 0);
    }

    // mask + scale + online softmax. C layout: row=quad*4+r, col=t*16+l16
    float sc[4][4];
    float mblk[4];
#pragma unroll
    for (int r = 0; r < 4; ++r) {
      int qpos = n * 64 + wid * 16 + quad * 4 + r;
      float mx = -1e30f;
#pragma unroll
      for (int t = 0; t < 4; ++t) {
        float s = sacc[t][r] * 0.125f;
        int kpos = kb * 64 + t * 16 + l16;
        if (kpos > qpos) s = -1e9f;
        sc[t][r] = s;
        mx = fmaxf(mx, s);
      }
#pragma unroll
      for (int off = 1; off < 16; off <<= 1) mx = fmaxf(mx, __shfl_xor(mx, off));
      mblk[r] = mx;
    }
    float alpha[4];
#pragma unroll
    for (int r = 0; r < 4; ++r) {
      float mnew = fmaxf(m_r[r], mblk[r]);
      alpha[r] = expf(m_r[r] - mnew);
      m_r[r] = mnew;
    }
#pragma unroll
    for (int r = 0; r < 4; ++r) {
      float sum = 0.f;
#pragma unroll
      for (int t = 0; t < 4; ++t) {
        float p = expf(sc[t][r] - m_r[r]);
        sc[t][r] = p;
        sum += p;
      }
#pragma unroll
      for (int off = 1; off < 16; off <<= 1) sum += __shfl_xor(sum, off);
      l_r[r] = l_r[r] * alpha[r] + sum;
    }
    // P (C-layout) -> LDS -> A-operand layout
#pragma unroll
    for (int r = 0; r < 4; ++r)
#pragma unroll
      for (int t = 0; t < 4; ++t)
        Ps[wid][(quad * 4 + r) * 64 + t * 16 + l16] = (bf16_t)sc[t][r];
#pragma unroll
    for (int t = 0; t < 4; ++t)
#pragma unroll
      for (int r = 0; r < 4; ++r)
        o_acc[t][r] *= alpha[r];
    __syncthreads();  // Ps/Vt visibility

    bf16x8 pa0 = *(const bf16x8*)&Ps[wid][l16 * 64 + quad * 8];
    bf16x8 pa1 = *(const bf16x8*)&Ps[wid][l16 * 64 + 32 + quad * 8];
#pragma unroll
    for (int t = 0; t < 4; ++t) {
      bf16x8 vb0 = *(const bf16x8*)&Vt[(t * 16 + l16) * 64 + quad * 8];
      bf16x8 vb1 = *(const bf16x8*)&Vt[(t * 16 + l16) * 64 + 32 + quad * 8];
      o_acc[t] = __builtin_amdgcn_mfma_f32_16x16x32_bf16(pa0, vb0, o_acc[t], 0, 0, 0);
      o_acc[t] = __builtin_amdgcn_mfma_f32_16x16x32_bf16(pa1, vb1, o_acc[t], 0, 0, 0);
    }
  }

#pragma unroll
  for (int t = 0; t < 4; ++t)
#pragma unroll
    for (int r = 0; r < 4; ++r) {
      int row = wid * 16 + quad * 4 + r;
      int col = t * 16 + l16;
      o[(rowbase + row) * D_ + hoff + col] = (bf16_t)(o_acc[t][r] / l_r[r]);
    }
}

// ---------------- launch ----------------
extern "C" void kernel_launch(void* const* d_in, const int* in_sizes, int n_in,
                              void* d_out, int out_size, void* d_ws, size_t ws_size,
                              hipStream_t stream) {
  const float* hs = (const float*)d_in[0];
  const int* pos  = (const int*)d_in[1];
  const float* wq = (const float*)d_in[2];
  const float* wk = (const float*)d_in[3];
  const float* wv = (const float*)d_in[4];
  const float* wo = (const float*)d_in[5];

  bf16_t* ws   = (bf16_t*)d_ws;
  bf16_t* hsb  = ws;                          // M_*D_
  bf16_t* wT   = hsb + (size_t)M_ * D_;       // 4*D_*D_   (wq,wk,wv,wo transposed)
  bf16_t* qkv  = wT + (size_t)4 * D_ * D_;    // 3*M_*D_
  bf16_t* attn = qkv + (size_t)3 * M_ * D_;   // M_*D_
  bf16_t* qw = qkv;
  bf16_t* kw = qkv + (size_t)M_ * D_;
  bf16_t* vw = qkv + (size_t)2 * M_ * D_;

  cast_bf16_kernel<<<(M_ * D_ / 4 + 255) / 256, 256, 0, stream>>>(hs, hsb, M_ * D_ / 4);
  transpose_cast_kernel<<<dim3(D_ / 32, D_ / 32, 4), dim3(32, 8), 0, stream>>>(wq, wk, wv, wo, wT);
  gemm128<true><<<dim3(D_ / 128, M_ / 128, 3), 256, 0, stream>>>(hsb, wT, (void*)qkv);
  rope_kernel<<<(M_ * H_ * 32) / 256, 256, 0, stream>>>(qw, kw, pos);
  attn_kernel<<<dim3(NB_, H_, B_), 256, 0, stream>>>(qw, kw, vw, attn);
  gemm128<false><<<dim3(D_ / 128, M_ / 128, 1), 256, 0, stream>>>(attn, wT + (size_t)3 * D_ * D_, d_out);
}

// Round 3
// 268.886 us; speedup vs baseline: 1.1998x; 1.1998x over previous
//
#include <hip/hip_runtime.h>
#include <cstdint>
#include <cstddef>

#define B_ 2
#define S_ 4096
#define D_ 1024
#define H_ 16
#define HD_ 64
#define NB_ 64
#define W_ 8
#define M_ (B_*S_)   // 8192

// 0.125 (1/sqrt(HD)) * log2(e), folded into Q during RoPE so softmax = exp2(S)
#define QSCALE 0.18033688011112042f

typedef __bf16 bf16_t;
typedef __bf16 bf16x8 __attribute__((ext_vector_type(8)));
typedef float f32x4 __attribute__((ext_vector_type(4)));

#define GLOAD_LDS16(gp, lp) \
  __builtin_amdgcn_global_load_lds((__attribute__((address_space(1))) void*)(gp), \
                                   (__attribute__((address_space(3))) void*)(lp), 16, 0, 0)

// ---------------- fp32 -> bf16 cast (hidden states) ----------------
__global__ void cast_bf16_kernel(const float* __restrict__ x, bf16_t* __restrict__ y, int n4) {
  int i = blockIdx.x * 256 + threadIdx.x;
  if (i >= n4) return;
  float4 v = ((const float4*)x)[i];
  union { bf16_t b[4]; uint2 u; } cv;
  cv.b[0] = (bf16_t)v.x; cv.b[1] = (bf16_t)v.y; cv.b[2] = (bf16_t)v.z; cv.b[3] = (bf16_t)v.w;
  ((uint2*)y)[i] = cv.u;
}

// ---------------- weight transpose + cast: wT[n][k] = (bf16)w[k][n] ----------------
__global__ void transpose_cast_kernel(const float* __restrict__ w0, const float* __restrict__ w1,
                                      const float* __restrict__ w2, const float* __restrict__ w3,
                                      bf16_t* __restrict__ out) {
  const float* w = (blockIdx.z == 0) ? w0 : (blockIdx.z == 1) ? w1 : (blockIdx.z == 2) ? w2 : w3;
  bf16_t* wt = out + (size_t)blockIdx.z * D_ * D_;
  __shared__ float tile[32][33];
  int x = blockIdx.x * 32 + threadIdx.x;
  int y0 = blockIdx.y * 32;
  for (int i = threadIdx.y; i < 32; i += 8)
    tile[i][threadIdx.x] = w[(size_t)(y0 + i) * D_ + x];
  __syncthreads();
  int x2 = blockIdx.y * 32 + threadIdx.x;   // k
  int y2 = blockIdx.x * 32;                 // n base
  for (int i = threadIdx.y; i < 32; i += 8)
    wt[(size_t)(y2 + i) * D_ + x2] = (bf16_t)tile[threadIdx.x][i];
}

// ---------------- GEMM: C[M,1024] = A[M,1024] @ Bt[n][k]^T ----------------
template<bool OBF>
__global__ __launch_bounds__(256) void gemm128(const bf16_t* __restrict__ A,
                                               const bf16_t* __restrict__ BtBase,
                                               void* __restrict__ Cbase) {
  const bf16_t* Bt = BtBase + (size_t)blockIdx.z * D_ * D_;
  const int mb = blockIdx.y * 128, nb = blockIdx.x * 128;
  const int tid = threadIdx.x;
  const int wid = tid >> 6, lane = tid & 63;
  const int quad = lane >> 4, l16 = lane & 15;
  const int wr = wid >> 1, wc = wid & 1;

  __shared__ bf16_t As[128 * 32];
  __shared__ bf16_t Bs[128 * 32];

  f32x4 acc[4][4];
#pragma unroll
  for (int mi = 0; mi < 4; ++mi)
#pragma unroll
    for (int ni = 0; ni < 4; ++ni)
      acc[mi][ni] = (f32x4){0.f, 0.f, 0.f, 0.f};

  const int acol = (lane & 3) * 8;
  const int arow0 = wid * 32 + (lane >> 2);
  const bf16_t* gA = A + (size_t)(mb + arow0) * D_ + acol;
  const bf16_t* gB = Bt + (size_t)(nb + arow0) * D_ + acol;

  for (int kt = 0; kt < 32; ++kt) {
    const int k0 = kt * 32;
    __syncthreads();
#pragma unroll
    for (int c = 0; c < 2; ++c) {
      GLOAD_LDS16(gA + (size_t)c * 16 * D_ + k0, As + (wid * 2 + c) * 512);
      GLOAD_LDS16(gB + (size_t)c * 16 * D_ + k0, Bs + (wid * 2 + c) * 512);
    }
    __syncthreads();
    bf16x8 af[4], bfr[4];
#pragma unroll
    for (int mi = 0; mi < 4; ++mi)
      af[mi] = *(const bf16x8*)&As[(wr * 64 + mi * 16 + l16) * 32 + quad * 8];
#pragma unroll
    for (int ni = 0; ni < 4; ++ni)
      bfr[ni] = *(const bf16x8*)&Bs[(wc * 64 + ni * 16 + l16) * 32 + quad * 8];
#pragma unroll
    for (int mi = 0; mi < 4; ++mi)
#pragma unroll
      for (int ni = 0; ni < 4; ++ni)
        acc[mi][ni] = __builtin_amdgcn_mfma_f32_16x16x32_bf16(af[mi], bfr[ni], acc[mi][ni], 0, 0, 0);
  }

  if constexpr (OBF) {
    bf16_t* Cp = (bf16_t*)Cbase + (size_t)blockIdx.z * M_ * D_;
#pragma unroll
    for (int mi = 0; mi < 4; ++mi)
#pragma unroll
      for (int ni = 0; ni < 4; ++ni)
#pragma unroll
        for (int r = 0; r < 4; ++r) {
          int row = mb + wr * 64 + mi * 16 + quad * 4 + r;
          int col = nb + wc * 64 + ni * 16 + l16;
          Cp[(size_t)row * D_ + col] = (bf16_t)acc[mi][ni][r];
        }
  } else {
    float* Cp = (float*)Cbase;
#pragma unroll
    for (int mi = 0; mi < 4; ++mi)
#pragma unroll
      for (int ni = 0; ni < 4; ++ni)
#pragma unroll
        for (int r = 0; r < 4; ++r) {
          int row = mb + wr * 64 + mi * 16 + quad * 4 + r;
          int col = nb + wc * 64 + ni * 16 + l16;
          Cp[(size_t)row * D_ + col] = acc[mi][ni][r];
        }
  }
}

// ---------------- RoPE (vectorized, in-place; Q gets QSCALE folded in) ----------------
__global__ void rope_kernel(bf16_t* __restrict__ q, bf16_t* __restrict__ k,
                            const int* __restrict__ pos_ids) {
  int idx = blockIdx.x * 256 + threadIdx.x;  // M_*H_*4 threads
  int a = idx & 3;
  int h = (idx >> 2) & (H_ - 1);
  int bs = idx >> 6;
  int pos = pos_ids[bs];
  size_t base = (size_t)bs * D_ + h * HD_ + a * 8;

  uint4 q1u = *(uint4*)(q + base), q2u = *(uint4*)(q + base + 32);
  uint4 k1u = *(uint4*)(k + base), k2u = *(uint4*)(k + base + 32);
  bf16_t* q1 = (bf16_t*)&q1u; bf16_t* q2 = (bf16_t*)&q2u;
  bf16_t* k1 = (bf16_t*)&k1u; bf16_t* k2 = (bf16_t*)&k2u;

#pragma unroll
  for (int j2 = 0; j2 < 8; ++j2) {
    int j = a * 8 + j2;
    float th = (float)pos * exp2f(-(float)j * 0.41524101186092034f);
    float sn, cs;
    sincosf(th, &sn, &cs);
    float x1 = (float)q1[j2], x2 = (float)q2[j2];
    q1[j2] = (bf16_t)((x1 * cs - x2 * sn) * QSCALE);
    q2[j2] = (bf16_t)((x2 * cs + x1 * sn) * QSCALE);
    float y1 = (float)k1[j2], y2 = (float)k2[j2];
    k1[j2] = (bf16_t)(y1 * cs - y2 * sn);
    k2[j2] = (bf16_t)(y2 * cs + y1 * sn);
  }
  *(uint4*)(q + base) = q1u; *(uint4*)(q + base + 32) = q2u;
  *(uint4*)(k + base) = k1u; *(uint4*)(k + base + 32) = k2u;
}

// ---------------- V global transpose with key-permutation ----------------
// vt[b][h][d][s'] where within each 64-block, position s'=p holds V[key=(p&3)*16+(p>>2)][d]
__global__ __launch_bounds__(256) void vt_kernel(const bf16_t* __restrict__ v,
                                                 bf16_t* __restrict__ vt) {
  const int kb = blockIdx.x, h = blockIdx.y, b = blockIdx.z;
  const int tid = threadIdx.x;
  __shared__ bf16_t Ls[64 * 72];
#pragma unroll
  for (int it = 0; it < 2; ++it) {
    int idx = it * 256 + tid;
    int r = idx >> 3, c = (idx & 7) * 8;
    *(uint4*)&Ls[r * 72 + c] = *(const uint4*)&v[((size_t)(b * S_ + kb * 64 + r)) * D_ + h * HD_ + c];
  }
  __syncthreads();
#pragma unroll
  for (int it = 0; it < 2; ++it) {
    int idx = it * 256 + tid;
    int d = idx >> 3, a = idx & 7;
    union { bf16_t bv[8]; uint4 u; } pk;
#pragma unroll
    for (int t = 0; t < 8; ++t) {
      int j = (t & 3) * 16 + 2 * a + (t >> 2);   // pi^-1(8a+t)
      pk.bv[t] = Ls[j * 72 + d];
    }
    *(uint4*)&vt[((size_t)(b * H_ + h) * HD_ + d) * S_ + kb * 64 + a * 8] = pk.u;
  }
}

// ---------------- block-sparse flash attention (no-max softmax, padded LDS) ----------------
__global__ __launch_bounds__(256) void attn_kernel(const bf16_t* __restrict__ q,
                                                   const bf16_t* __restrict__ k,
                                                   const bf16_t* __restrict__ vt,
                                                   bf16_t* __restrict__ o) {
  const int n = blockIdx.x, h = blockIdx.y, b = blockIdx.z;
  const int tid = threadIdx.x;
  const int wid = tid >> 6, lane = tid & 63;
  const int quad = lane >> 4, l16 = lane & 15;

  __shared__ bf16_t Ks[64 * 72];
  __shared__ bf16_t Vs[64 * 72];
  __shared__ bf16_t Ps[4][16 * 72];

  const size_t rowbase = (size_t)(b * S_ + n * 64);
  const size_t hoff = (size_t)h * HD_;
  const size_t vtbase = (size_t)(b * H_ + h) * HD_ * S_;

  // Q fragment straight from global (scaled in rope); row = wid*16+l16
  const bf16_t* qrow = q + (rowbase + wid * 16 + l16) * D_ + hoff;
  bf16x8 aq0 = *(const bf16x8*)(qrow + quad * 8);
  bf16x8 aq1 = *(const bf16x8*)(qrow + 32 + quad * 8);

  f32x4 o_acc[4];
#pragma unroll
  for (int t = 0; t < 4; ++t) o_acc[t] = (f32x4){0.f, 0.f, 0.f, 0.f};
  float lsum[4] = {0.f, 0.f, 0.f, 0.f};

  const int srow = tid >> 3;          // staging: 32 rows per pass
  const int scol = (tid & 7) * 8;

  const int kb0 = (n >= W_ - 1) ? n - (W_ - 1) : 0;
  for (int kb = kb0; kb <= n; ++kb) {
    __syncthreads();
    const size_t krow = (size_t)(b * S_ + kb * 64);
#pragma unroll
    for (int it = 0; it < 2; ++it) {
      int r = it * 32 + srow;
      *(uint4*)&Ks[r * 72 + scol] = *(const uint4*)&k[(krow + r) * D_ + hoff + scol];
      *(uint4*)&Vs[r * 72 + scol] = *(const uint4*)&vt[vtbase + (size_t)r * S_ + kb * 64 + scol];
    }
    __syncthreads();

    // S = Q @ K^T  (wave: 16 q-rows x 64 keys)
    f32x4 sacc[4];
#pragma unroll
    for (int t = 0; t < 4; ++t) sacc[t] = (f32x4){0.f, 0.f, 0.f, 0.f};
#pragma unroll
    for (int t = 0; t < 4; ++t) {
      bf16x8 bk0 = *(const bf16x8*)&Ks[(t * 16 + l16) * 72 + quad * 8];
      bf16x8 bk1 = *(const bf16x8*)&Ks[(t * 16 + l16) * 72 + 32 + quad * 8];
      sacc[t] = __builtin_amdgcn_mfma_f32_16x16x32_bf16(aq0, bk0, sacc[t], 0, 0, 0);
      sacc[t] = __builtin_amdgcn_mfma_f32_16x16x32_bf16(aq1, bk1, sacc[t], 0, 0, 0);
    }

    // p = exp2(S) (scale pre-folded); mask only on diagonal block; pack 4 bf16 -> b64
    const bool diag = (kb == n);
#pragma unroll
    for (int r = 0; r < 4; ++r) {
      int qpos = wid * 16 + quad * 4 + r;
      union { bf16_t bv[4]; uint2 u; } pk;
      float rs = 0.f;
#pragma unroll
      for (int t = 0; t < 4; ++t) {
        float p = exp2f(sacc[t][r]);
        if (diag && (t * 16 + l16 > qpos)) p = 0.f;
        rs += p;
        pk.bv[t] = (bf16_t)p;
      }
      lsum[r] += rs;
      // col' = l16*4 + t  (pi-permuted keys)
      *(uint2*)&Ps[wid][(quad * 4 + r) * 72 + l16 * 4] = pk.u;
    }

    // O += P @ V (keys pi-permuted on both sides)
    bf16x8 pa0 = *(const bf16x8*)&Ps[wid][l16 * 72 + quad * 8];
    bf16x8 pa1 = *(const bf16x8*)&Ps[wid][l16 * 72 + 32 + quad * 8];
#pragma unroll
    for (int t = 0; t < 4; ++t) {
      bf16x8 vb0 = *(const bf16x8*)&Vs[(t * 16 + l16) * 72 + quad * 8];
      bf16x8 vb1 = *(const bf16x8*)&Vs[(t * 16 + l16) * 72 + 32 + quad * 8];
      o_acc[t] = __builtin_amdgcn_mfma_f32_16x16x32_bf16(pa0, vb0, o_acc[t], 0, 0, 0);
      o_acc[t] = __builtin_amdgcn_mfma_f32_16x16x32_bf16(pa1, vb1, o_acc[t], 0, 0, 0);
    }
  }

  // row-sum across the 16 l16 lanes (once, at the end)
  float inv[4];
#pragma unroll
  for (int r = 0; r < 4; ++r) {
    float s = lsum[r];
#pragma unroll
    for (int off = 1; off < 16; off <<= 1) s += __shfl_xor(s, off);
    inv[r] = 1.f / s;
  }

#pragma unroll
  for (int t = 0; t < 4; ++t)
#pragma unroll
    for (int r = 0; r < 4; ++r) {
      int row = wid * 16 + quad * 4 + r;
      int col = t * 16 + l16;
      o[(rowbase + row) * D_ + hoff + col] = (bf16_t)(o_acc[t][r] * inv[r]);
    }
}

// ---------------- launch ----------------
extern "C" void kernel_launch(void* const* d_in, const int* in_sizes, int n_in,
                              void* d_out, int out_size, void* d_ws, size_t ws_size,
                              hipStream_t stream) {
  const float* hs = (const float*)d_in[0];
  const int* pos  = (const int*)d_in[1];
  const float* wq = (const float*)d_in[2];
  const float* wk = (const float*)d_in[3];
  const float* wv = (const float*)d_in[4];
  const float* wo = (const float*)d_in[5];

  bf16_t* ws   = (bf16_t*)d_ws;
  bf16_t* hsb  = ws;                          // M_*D_
  bf16_t* wT   = hsb + (size_t)M_ * D_;       // 4*D_*D_
  bf16_t* qkv  = wT + (size_t)4 * D_ * D_;    // 3*M_*D_
  bf16_t* attn = qkv + (size_t)3 * M_ * D_;   // M_*D_
  // vtg ALIASES hsb: hidden-states bf16 buffer is dead after the QKV GEMM.
  // Keeps total ws usage at the round-1 footprint (92.3 MB) — appending a new
  // buffer overflowed ws_size and crashed (round-2 abort).
  bf16_t* vtg  = hsb;
  bf16_t* qw = qkv;
  bf16_t* kw = qkv + (size_t)M_ * D_;
  bf16_t* vw = qkv + (size_t)2 * M_ * D_;

  cast_bf16_kernel<<<(M_ * D_ / 4 + 255) / 256, 256, 0, stream>>>(hs, hsb, M_ * D_ / 4);
  transpose_cast_kernel<<<dim3(D_ / 32, D_ / 32, 4), dim3(32, 8), 0, stream>>>(wq, wk, wv, wo, wT);
  gemm128<true><<<dim3(D_ / 128, M_ / 128, 3), 256, 0, stream>>>(hsb, wT, (void*)qkv);
  rope_kernel<<<(M_ * H_ * 4) / 256, 256, 0, stream>>>(qw, kw, pos);
  vt_kernel<<<dim3(NB_, H_, B_), 256, 0, stream>>>(vw, vtg);
  attn_kernel<<<dim3(NB_, H_, B_), 256, 0, stream>>>(qw, kw, vtg, attn);
  gemm128<false><<<dim3(D_ / 128, M_ / 128, 1), 256, 0, stream>>>(attn, wT + (size_t)3 * D_ * D_, d_out);
}

// Round 4
// 256.054 us; speedup vs baseline: 1.2599x; 1.0501x over previous
//
#include <hip/hip_runtime.h>
#include <cstdint>
#include <cstddef>

#define B_ 2
#define S_ 4096
#define D_ 1024
#define H_ 16
#define HD_ 64
#define NB_ 64
#define W_ 8
#define M_ (B_*S_)   // 8192

// 0.125 (1/sqrt(HD)) * log2(e), folded into Q so attention softmax = exp2(S)
#define QSCALE 0.18033688011112042f
#define LOG2_10000_OVER_32 0.41524101186092034f

typedef __bf16 bf16_t;
typedef __bf16 bf16x8 __attribute__((ext_vector_type(8)));
typedef float f32x4 __attribute__((ext_vector_type(4)));

#define GLOAD_LDS16(gp, lp) \
  __builtin_amdgcn_global_load_lds((__attribute__((address_space(1))) void*)(gp), \
                                   (__attribute__((address_space(3))) void*)(lp), 16, 0, 0)

// ---------------- fp32 -> bf16 cast (hidden states) ----------------
__global__ void cast_bf16_kernel(const float* __restrict__ x, bf16_t* __restrict__ y, int n4) {
  int i = blockIdx.x * 256 + threadIdx.x;
  if (i >= n4) return;
  float4 v = ((const float4*)x)[i];
  union { bf16_t b[4]; uint2 u; } cv;
  cv.b[0] = (bf16_t)v.x; cv.b[1] = (bf16_t)v.y; cv.b[2] = (bf16_t)v.z; cv.b[3] = (bf16_t)v.w;
  ((uint2*)y)[i] = cv.u;
}

// ---------------- weight transpose + cast: wT[n][k] = (bf16)w[k][n] ----------------
__global__ void transpose_cast_kernel(const float* __restrict__ w0, const float* __restrict__ w1,
                                      const float* __restrict__ w2, const float* __restrict__ w3,
                                      bf16_t* __restrict__ out) {
  const float* w = (blockIdx.z == 0) ? w0 : (blockIdx.z == 1) ? w1 : (blockIdx.z == 2) ? w2 : w3;
  bf16_t* wt = out + (size_t)blockIdx.z * D_ * D_;
  __shared__ float tile[32][33];
  int x = blockIdx.x * 32 + threadIdx.x;
  int y0 = blockIdx.y * 32;
  for (int i = threadIdx.y; i < 32; i += 8)
    tile[i][threadIdx.x] = w[(size_t)(y0 + i) * D_ + x];
  __syncthreads();
  int x2 = blockIdx.y * 32 + threadIdx.x;   // k
  int y2 = blockIdx.x * 32;                 // n base
  for (int i = threadIdx.y; i < 32; i += 8)
    wt[(size_t)(y2 + i) * D_ + x2] = (bf16_t)tile[threadIdx.x][i];
}

// ---------------- GEMM: C[M,1024] = A[M,1024] @ Bt[n][k]^T ----------------
// OBF=true: bf16 output, z=0 -> Q (rope+QSCALE fused), z=1 -> K (rope fused), z=2 -> V plain
// OBF=false: fp32 output, no rope
template<bool OBF>
__global__ __launch_bounds__(256) void gemm128(const bf16_t* __restrict__ A,
                                               const bf16_t* __restrict__ BtBase,
                                               void* __restrict__ Cbase,
                                               const int* __restrict__ pos_ids) {
  const bf16_t* Bt = BtBase + (size_t)blockIdx.z * D_ * D_;
  const int mb = blockIdx.y * 128, nb = blockIdx.x * 128;
  const int tid = threadIdx.x;
  const int wid = tid >> 6, lane = tid & 63;
  const int quad = lane >> 4, l16 = lane & 15;
  const int wr = wid >> 1, wc = wid & 1;

  __shared__ bf16_t As[128 * 32];
  __shared__ bf16_t Bs[128 * 32];

  f32x4 acc[4][4];
#pragma unroll
  for (int mi = 0; mi < 4; ++mi)
#pragma unroll
    for (int ni = 0; ni < 4; ++ni)
      acc[mi][ni] = (f32x4){0.f, 0.f, 0.f, 0.f};

  const int acol = (lane & 3) * 8;
  const int arow0 = wid * 32 + (lane >> 2);
  const bf16_t* gA = A + (size_t)(mb + arow0) * D_ + acol;
  const bf16_t* gB = Bt + (size_t)(nb + arow0) * D_ + acol;

  for (int kt = 0; kt < 32; ++kt) {
    const int k0 = kt * 32;
    __syncthreads();
#pragma unroll
    for (int c = 0; c < 2; ++c) {
      GLOAD_LDS16(gA + (size_t)c * 16 * D_ + k0, As + (wid * 2 + c) * 512);
      GLOAD_LDS16(gB + (size_t)c * 16 * D_ + k0, Bs + (wid * 2 + c) * 512);
    }
    __syncthreads();
    bf16x8 af[4], bfr[4];
#pragma unroll
    for (int mi = 0; mi < 4; ++mi)
      af[mi] = *(const bf16x8*)&As[(wr * 64 + mi * 16 + l16) * 32 + quad * 8];
#pragma unroll
    for (int ni = 0; ni < 4; ++ni)
      bfr[ni] = *(const bf16x8*)&Bs[(wc * 64 + ni * 16 + l16) * 32 + quad * 8];
#pragma unroll
    for (int mi = 0; mi < 4; ++mi)
#pragma unroll
      for (int ni = 0; ni < 4; ++ni)
        acc[mi][ni] = __builtin_amdgcn_mfma_f32_16x16x32_bf16(af[mi], bfr[ni], acc[mi][ni], 0, 0, 0);
  }

  if constexpr (OBF) {
    bf16_t* Cp = (bf16_t*)Cbase + (size_t)blockIdx.z * M_ * D_;
    if (blockIdx.z < 2) {
      // fused RoPE: pair (j, j+32) within a head == (acc[mi][ni], acc[mi][ni+2]), same lane
      const float qsc = (blockIdx.z == 0) ? QSCALE : 1.0f;
      float invf[2];
#pragma unroll
      for (int ni = 0; ni < 2; ++ni)
        invf[ni] = __builtin_exp2f(-(float)(ni * 16 + l16) * LOG2_10000_OVER_32);
#pragma unroll
      for (int mi = 0; mi < 4; ++mi)
#pragma unroll
        for (int r = 0; r < 4; ++r) {
          int row = mb + wr * 64 + mi * 16 + quad * 4 + r;
          float fpos = (float)pos_ids[row];
#pragma unroll
          for (int ni = 0; ni < 2; ++ni) {
            float sn, cs;
            __sincosf(fpos * invf[ni], &sn, &cs);
            float x1 = acc[mi][ni][r], x2 = acc[mi][ni + 2][r];
            int col = nb + wc * 64 + ni * 16 + l16;
            Cp[(size_t)row * D_ + col]      = (bf16_t)((x1 * cs - x2 * sn) * qsc);
            Cp[(size_t)row * D_ + col + 32] = (bf16_t)((x2 * cs + x1 * sn) * qsc);
          }
        }
    } else {
#pragma unroll
      for (int mi = 0; mi < 4; ++mi)
#pragma unroll
        for (int ni = 0; ni < 4; ++ni)
#pragma unroll
          for (int r = 0; r < 4; ++r) {
            int row = mb + wr * 64 + mi * 16 + quad * 4 + r;
            int col = nb + wc * 64 + ni * 16 + l16;
            Cp[(size_t)row * D_ + col] = (bf16_t)acc[mi][ni][r];
          }
    }
  } else {
    float* Cp = (float*)Cbase;
#pragma unroll
    for (int mi = 0; mi < 4; ++mi)
#pragma unroll
      for (int ni = 0; ni < 4; ++ni)
#pragma unroll
        for (int r = 0; r < 4; ++r) {
          int row = mb + wr * 64 + mi * 16 + quad * 4 + r;
          int col = nb + wc * 64 + ni * 16 + l16;
          Cp[(size_t)row * D_ + col] = acc[mi][ni][r];
        }
  }
}

// ---------------- V global transpose with key-permutation ----------------
// vt[b][h][d][s'] where within each 64-block, position s'=p holds V[key=(p&3)*16+(p>>2)][d]
__global__ __launch_bounds__(256) void vt_kernel(const bf16_t* __restrict__ v,
                                                 bf16_t* __restrict__ vt) {
  const int kb = blockIdx.x, h = blockIdx.y, b = blockIdx.z;
  const int tid = threadIdx.x;
  __shared__ bf16_t Ls[64 * 72];
#pragma unroll
  for (int it = 0; it < 2; ++it) {
    int idx = it * 256 + tid;
    int r = idx >> 3, c = (idx & 7) * 8;
    *(uint4*)&Ls[r * 72 + c] = *(const uint4*)&v[((size_t)(b * S_ + kb * 64 + r)) * D_ + h * HD_ + c];
  }
  __syncthreads();
#pragma unroll
  for (int it = 0; it < 2; ++it) {
    int idx = it * 256 + tid;
    int d = idx >> 3, a = idx & 7;
    union { bf16_t bv[8]; uint4 u; } pk;
#pragma unroll
    for (int t = 0; t < 8; ++t) {
      int j = (t & 3) * 16 + 2 * a + (t >> 2);   // pi^-1(8a+t)
      pk.bv[t] = Ls[j * 72 + d];
    }
    *(uint4*)&vt[((size_t)(b * H_ + h) * HD_ + d) * S_ + kb * 64 + a * 8] = pk.u;
  }
}

// ---------------- block-sparse flash attention (no-max softmax, padded LDS) ----------------
__global__ __launch_bounds__(256) void attn_kernel(const bf16_t* __restrict__ q,
                                                   const bf16_t* __restrict__ k,
                                                   const bf16_t* __restrict__ vt,
                                                   bf16_t* __restrict__ o) {
  const int n = blockIdx.x, h = blockIdx.y, b = blockIdx.z;
  const int tid = threadIdx.x;
  const int wid = tid >> 6, lane = tid & 63;
  const int quad = lane >> 4, l16 = lane & 15;

  __shared__ bf16_t Ks[64 * 72];
  __shared__ bf16_t Vs[64 * 72];
  __shared__ bf16_t Ps[4][16 * 72];

  const size_t rowbase = (size_t)(b * S_ + n * 64);
  const size_t hoff = (size_t)h * HD_;
  const size_t vtbase = (size_t)(b * H_ + h) * HD_ * S_;

  const bf16_t* qrow = q + (rowbase + wid * 16 + l16) * D_ + hoff;
  bf16x8 aq0 = *(const bf16x8*)(qrow + quad * 8);
  bf16x8 aq1 = *(const bf16x8*)(qrow + 32 + quad * 8);

  f32x4 o_acc[4];
#pragma unroll
  for (int t = 0; t < 4; ++t) o_acc[t] = (f32x4){0.f, 0.f, 0.f, 0.f};
  float lsum[4] = {0.f, 0.f, 0.f, 0.f};

  const int srow = tid >> 3;
  const int scol = (tid & 7) * 8;

  const int kb0 = (n >= W_ - 1) ? n - (W_ - 1) : 0;
  for (int kb = kb0; kb <= n; ++kb) {
    __syncthreads();
    const size_t krow = (size_t)(b * S_ + kb * 64);
#pragma unroll
    for (int it = 0; it < 2; ++it) {
      int r = it * 32 + srow;
      *(uint4*)&Ks[r * 72 + scol] = *(const uint4*)&k[(krow + r) * D_ + hoff + scol];
      *(uint4*)&Vs[r * 72 + scol] = *(const uint4*)&vt[vtbase + (size_t)r * S_ + kb * 64 + scol];
    }
    __syncthreads();

    f32x4 sacc[4];
#pragma unroll
    for (int t = 0; t < 4; ++t) sacc[t] = (f32x4){0.f, 0.f, 0.f, 0.f};
#pragma unroll
    for (int t = 0; t < 4; ++t) {
      bf16x8 bk0 = *(const bf16x8*)&Ks[(t * 16 + l16) * 72 + quad * 8];
      bf16x8 bk1 = *(const bf16x8*)&Ks[(t * 16 + l16) * 72 + 32 + quad * 8];
      sacc[t] = __builtin_amdgcn_mfma_f32_16x16x32_bf16(aq0, bk0, sacc[t], 0, 0, 0);
      sacc[t] = __builtin_amdgcn_mfma_f32_16x16x32_bf16(aq1, bk1, sacc[t], 0, 0, 0);
    }

    const bool diag = (kb == n);
#pragma unroll
    for (int r = 0; r < 4; ++r) {
      int qpos = wid * 16 + quad * 4 + r;
      union { bf16_t bv[4]; uint2 u; } pk;
      float rs = 0.f;
#pragma unroll
      for (int t = 0; t < 4; ++t) {
        float p = exp2f(sacc[t][r]);
        if (diag && (t * 16 + l16 > qpos)) p = 0.f;
        rs += p;
        pk.bv[t] = (bf16_t)p;
      }
      lsum[r] += rs;
      *(uint2*)&Ps[wid][(quad * 4 + r) * 72 + l16 * 4] = pk.u;
    }

    bf16x8 pa0 = *(const bf16x8*)&Ps[wid][l16 * 72 + quad * 8];
    bf16x8 pa1 = *(const bf16x8*)&Ps[wid][l16 * 72 + 32 + quad * 8];
#pragma unroll
    for (int t = 0; t < 4; ++t) {
      bf16x8 vb0 = *(const bf16x8*)&Vs[(t * 16 + l16) * 72 + quad * 8];
      bf16x8 vb1 = *(const bf16x8*)&Vs[(t * 16 + l16) * 72 + 32 + quad * 8];
      o_acc[t] = __builtin_amdgcn_mfma_f32_16x16x32_bf16(pa0, vb0, o_acc[t], 0, 0, 0);
      o_acc[t] = __builtin_amdgcn_mfma_f32_16x16x32_bf16(pa1, vb1, o_acc[t], 0, 0, 0);
    }
  }

  float inv[4];
#pragma unroll
  for (int r = 0; r < 4; ++r) {
    float s = lsum[r];
#pragma unroll
    for (int off = 1; off < 16; off <<= 1) s += __shfl_xor(s, off);
    inv[r] = 1.f / s;
  }

#pragma unroll
  for (int t = 0; t < 4; ++t)
#pragma unroll
    for (int r = 0; r < 4; ++r) {
      int row = wid * 16 + quad * 4 + r;
      int col = t * 16 + l16;
      o[(rowbase + row) * D_ + hoff + col] = (bf16_t)(o_acc[t][r] * inv[r]);
    }
}

// ---------------- launch ----------------
extern "C" void kernel_launch(void* const* d_in, const int* in_sizes, int n_in,
                              void* d_out, int out_size, void* d_ws, size_t ws_size,
                              hipStream_t stream) {
  const float* hs = (const float*)d_in[0];
  const int* pos  = (const int*)d_in[1];
  const float* wq = (const float*)d_in[2];
  const float* wk = (const float*)d_in[3];
  const float* wv = (const float*)d_in[4];
  const float* wo = (const float*)d_in[5];

  bf16_t* ws   = (bf16_t*)d_ws;
  bf16_t* hsb  = ws;                          // M_*D_
  bf16_t* wT   = hsb + (size_t)M_ * D_;       // 4*D_*D_
  bf16_t* qkv  = wT + (size_t)4 * D_ * D_;    // 3*M_*D_
  bf16_t* attn = qkv + (size_t)3 * M_ * D_;   // M_*D_
  // vtg aliases hsb: hidden-states bf16 buffer is dead after the QKV GEMM
  // (ws footprint must stay at 92.3 MB — appending a buffer overflowed ws_size, round-2 abort)
  bf16_t* vtg  = hsb;
  bf16_t* qw = qkv;
  bf16_t* kw = qkv + (size_t)M_ * D_;
  bf16_t* vw = qkv + (size_t)2 * M_ * D_;

  cast_bf16_kernel<<<(M_ * D_ / 4 + 255) / 256, 256, 0, stream>>>(hs, hsb, M_ * D_ / 4);
  transpose_cast_kernel<<<dim3(D_ / 32, D_ / 32, 4), dim3(32, 8), 0, stream>>>(wq, wk, wv, wo, wT);
  gemm128<true><<<dim3(D_ / 128, M_ / 128, 3), 256, 0, stream>>>(hsb, wT, (void*)qkv, pos);
  vt_kernel<<<dim3(NB_, H_, B_), 256, 0, stream>>>(vw, vtg);
  attn_kernel<<<dim3(NB_, H_, B_), 256, 0, stream>>>(qw, kw, vtg, attn);
  gemm128<false><<<dim3(D_ / 128, M_ / 128, 1), 256, 0, stream>>>(attn, wT + (size_t)3 * D_ * D_, d_out, pos);
}

// Round 5
// 244.812 us; speedup vs baseline: 1.3178x; 1.0459x over previous
//
#include <hip/hip_runtime.h>
#include <cstdint>
#include <cstddef>

#define B_ 2
#define S_ 4096
#define D_ 1024
#define H_ 16
#define HD_ 64
#define NB_ 64
#define W_ 8
#define M_ (B_*S_)   // 8192

// 0.125 (1/sqrt(HD)) * log2(e), folded into Q so attention softmax = exp2(S)
#define QSCALE 0.18033688011112042f
#define LOG2_10000_OVER_32 0.41524101186092034f

typedef __bf16 bf16_t;
typedef __bf16 bf16x8 __attribute__((ext_vector_type(8)));
typedef float f32x4 __attribute__((ext_vector_type(4)));

#define GLOAD_LDS16(gp, lp) \
  __builtin_amdgcn_global_load_lds((__attribute__((address_space(1))) void*)(gp), \
                                   (__attribute__((address_space(3))) void*)(lp), 16, 0, 0)

// ---------------- fp32 -> bf16 cast (hidden states) ----------------
__global__ void cast_bf16_kernel(const float* __restrict__ x, bf16_t* __restrict__ y, int n4) {
  int i = blockIdx.x * 256 + threadIdx.x;
  if (i >= n4) return;
  float4 v = ((const float4*)x)[i];
  union { bf16_t b[4]; uint2 u; } cv;
  cv.b[0] = (bf16_t)v.x; cv.b[1] = (bf16_t)v.y; cv.b[2] = (bf16_t)v.z; cv.b[3] = (bf16_t)v.w;
  ((uint2*)y)[i] = cv.u;
}

// ---------------- weight transpose + cast: wT[n][k] = (bf16)w[k][n] ----------------
__global__ void transpose_cast_kernel(const float* __restrict__ w0, const float* __restrict__ w1,
                                      const float* __restrict__ w2, const float* __restrict__ w3,
                                      bf16_t* __restrict__ out) {
  const float* w = (blockIdx.z == 0) ? w0 : (blockIdx.z == 1) ? w1 : (blockIdx.z == 2) ? w2 : w3;
  bf16_t* wt = out + (size_t)blockIdx.z * D_ * D_;
  __shared__ float tile[32][33];
  int x = blockIdx.x * 32 + threadIdx.x;
  int y0 = blockIdx.y * 32;
  for (int i = threadIdx.y; i < 32; i += 8)
    tile[i][threadIdx.x] = w[(size_t)(y0 + i) * D_ + x];
  __syncthreads();
  int x2 = blockIdx.y * 32 + threadIdx.x;   // k
  int y2 = blockIdx.x * 32;                 // n base
  for (int i = threadIdx.y; i < 32; i += 8)
    wt[(size_t)(y2 + i) * D_ + x2] = (bf16_t)tile[threadIdx.x][i];
}

// ---------------- GEMM: C[M,1024] = A[M,1024] @ Bt[n][k]^T ----------------
// OBF=true:  z=0 -> Q (rope+QSCALE fused, to Cbase), z=1 -> K (rope, to Cbase),
//            z=2 -> V written TRANSPOSED + pi-permuted into vt_out (vt[b][h][d][s'])
// OBF=false: fp32 output, plain epilogue
template<bool OBF>
__global__ __launch_bounds__(256) void gemm128(const bf16_t* __restrict__ A,
                                               const bf16_t* __restrict__ BtBase,
                                               void* __restrict__ Cbase,
                                               bf16_t* __restrict__ vt_out,
                                               const int* __restrict__ pos_ids) {
  const bf16_t* Bt = BtBase + (size_t)blockIdx.z * D_ * D_;
  const int mb = blockIdx.y * 128, nb = blockIdx.x * 128;
  const int tid = threadIdx.x;
  const int wid = tid >> 6, lane = tid & 63;
  const int quad = lane >> 4, l16 = lane & 15;
  const int wr = wid >> 1, wc = wid & 1;

  __shared__ bf16_t As[128 * 32];
  __shared__ bf16_t Bs[128 * 32];

  f32x4 acc[4][4];
#pragma unroll
  for (int mi = 0; mi < 4; ++mi)
#pragma unroll
    for (int ni = 0; ni < 4; ++ni)
      acc[mi][ni] = (f32x4){0.f, 0.f, 0.f, 0.f};

  const int acol = (lane & 3) * 8;
  const int arow0 = wid * 32 + (lane >> 2);
  const bf16_t* gA = A + (size_t)(mb + arow0) * D_ + acol;
  const bf16_t* gB = Bt + (size_t)(nb + arow0) * D_ + acol;

  for (int kt = 0; kt < 32; ++kt) {
    const int k0 = kt * 32;
    __syncthreads();
#pragma unroll
    for (int c = 0; c < 2; ++c) {
      GLOAD_LDS16(gA + (size_t)c * 16 * D_ + k0, As + (wid * 2 + c) * 512);
      GLOAD_LDS16(gB + (size_t)c * 16 * D_ + k0, Bs + (wid * 2 + c) * 512);
    }
    __syncthreads();
    bf16x8 af[4], bfr[4];
#pragma unroll
    for (int mi = 0; mi < 4; ++mi)
      af[mi] = *(const bf16x8*)&As[(wr * 64 + mi * 16 + l16) * 32 + quad * 8];
#pragma unroll
    for (int ni = 0; ni < 4; ++ni)
      bfr[ni] = *(const bf16x8*)&Bs[(wc * 64 + ni * 16 + l16) * 32 + quad * 8];
#pragma unroll
    for (int mi = 0; mi < 4; ++mi)
#pragma unroll
      for (int ni = 0; ni < 4; ++ni)
        acc[mi][ni] = __builtin_amdgcn_mfma_f32_16x16x32_bf16(af[mi], bfr[ni], acc[mi][ni], 0, 0, 0);
  }

  if constexpr (OBF) {
    if (blockIdx.z < 2) {
      bf16_t* Cp = (bf16_t*)Cbase + (size_t)blockIdx.z * M_ * D_;
      // fused RoPE: pair (j, j+32) within a head == (acc[mi][ni], acc[mi][ni+2]), same lane
      const float qsc = (blockIdx.z == 0) ? QSCALE : 1.0f;
      float invf[2];
#pragma unroll
      for (int ni = 0; ni < 2; ++ni)
        invf[ni] = __builtin_exp2f(-(float)(ni * 16 + l16) * LOG2_10000_OVER_32);
#pragma unroll
      for (int mi = 0; mi < 4; ++mi)
#pragma unroll
        for (int r = 0; r < 4; ++r) {
          int row = mb + wr * 64 + mi * 16 + quad * 4 + r;
          float fpos = (float)pos_ids[row];
#pragma unroll
          for (int ni = 0; ni < 2; ++ni) {
            float sn, cs;
            __sincosf(fpos * invf[ni], &sn, &cs);
            float x1 = acc[mi][ni][r], x2 = acc[mi][ni + 2][r];
            int col = nb + wc * 64 + ni * 16 + l16;
            Cp[(size_t)row * D_ + col]      = (bf16_t)((x1 * cs - x2 * sn) * qsc);
            Cp[(size_t)row * D_ + col + 32] = (bf16_t)((x2 * cs + x1 * sn) * qsc);
          }
        }
    } else {
      // V: write transposed + pi-permuted. Row j within 64-block lands at
      // pi(j) = (j%16)*4 + j/16 = quad*16 + r*4 + mi  -> contiguous 16 per (lane, ni)
      int g = 2 * blockIdx.y + wr;        // 64-row block index in M
      int bb = g >> 6, sblk = g & 63;     // batch, seq-block
      int hh = 2 * blockIdx.x + wc;       // head
      size_t vbase = (size_t)(bb * H_ + hh) * HD_ * S_;
#pragma unroll
      for (int ni = 0; ni < 4; ++ni) {
        int d = ni * 16 + l16;
        union { bf16_t bv[16]; uint4 u[2]; } pk;
#pragma unroll
        for (int r = 0; r < 4; ++r)
#pragma unroll
          for (int mi = 0; mi < 4; ++mi)
            pk.bv[r * 4 + mi] = (bf16_t)acc[mi][ni][r];
        size_t addr = vbase + (size_t)d * S_ + sblk * 64 + quad * 16;
        *(uint4*)&vt_out[addr]     = pk.u[0];
        *(uint4*)&vt_out[addr + 8] = pk.u[1];
      }
    }
  } else {
    float* Cp = (float*)Cbase;
#pragma unroll
    for (int mi = 0; mi < 4; ++mi)
#pragma unroll
      for (int ni = 0; ni < 4; ++ni)
#pragma unroll
        for (int r = 0; r < 4; ++r) {
          int row = mb + wr * 64 + mi * 16 + quad * 4 + r;
          int col = nb + wc * 64 + ni * 16 + l16;
          Cp[(size_t)row * D_ + col] = acc[mi][ni][r];
        }
  }
}

// ---------------- block-sparse flash attention: 2 q-blocks / workgroup ----------------
// K-window union for q-blocks (2m, 2m+1) = 9 k-blocks; K/V staged once, used by both.
__global__ __launch_bounds__(256) void attn_kernel(const bf16_t* __restrict__ q,
                                                   const bf16_t* __restrict__ k,
                                                   const bf16_t* __restrict__ vt,
                                                   bf16_t* __restrict__ o) {
  const int m = blockIdx.x, h = blockIdx.y, b = blockIdx.z;
  const int n0 = m * 2, n1 = n0 + 1;
  const int tid = threadIdx.x;
  const int wid = tid >> 6, lane = tid & 63;
  const int quad = lane >> 4, l16 = lane & 15;

  __shared__ bf16_t Ks[64 * 72];
  __shared__ bf16_t Vs[64 * 72];
  __shared__ bf16_t Ps[4][16 * 72];

  const size_t hoff = (size_t)h * HD_;
  const size_t vtbase = (size_t)(b * H_ + h) * HD_ * S_;
  const size_t rowb[2] = {(size_t)(b * S_ + n0 * 64), (size_t)(b * S_ + n1 * 64)};

  bf16x8 aq[2][2];
#pragma unroll
  for (int x = 0; x < 2; ++x) {
    const bf16_t* qr = q + (rowb[x] + wid * 16 + l16) * D_ + hoff;
    aq[x][0] = *(const bf16x8*)(qr + quad * 8);
    aq[x][1] = *(const bf16x8*)(qr + 32 + quad * 8);
  }

  f32x4 o_acc[2][4];
  float lsum[2][4];
#pragma unroll
  for (int x = 0; x < 2; ++x)
#pragma unroll
    for (int t = 0; t < 4; ++t) {
      o_acc[x][t] = (f32x4){0.f, 0.f, 0.f, 0.f};
      lsum[x][t] = 0.f;
    }

  const int srow = tid >> 3;
  const int scol = (tid & 7) * 8;

  const int kb0 = (n0 >= W_ - 1) ? n0 - (W_ - 1) : 0;
  for (int kb = kb0; kb <= n1; ++kb) {
    __syncthreads();
    const size_t krow = (size_t)(b * S_ + kb * 64);
#pragma unroll
    for (int it = 0; it < 2; ++it) {
      int r = it * 32 + srow;
      *(uint4*)&Ks[r * 72 + scol] = *(const uint4*)&k[(krow + r) * D_ + hoff + scol];
      *(uint4*)&Vs[r * 72 + scol] = *(const uint4*)&vt[vtbase + (size_t)r * S_ + kb * 64 + scol];
    }
    __syncthreads();

#pragma unroll
    for (int x = 0; x < 2; ++x) {
      const int nx = n0 + x;
      if (x == 0 ? (kb > n0) : (kb < n1 - (W_ - 1))) continue;  // wave-uniform

      f32x4 sacc[4];
#pragma unroll
      for (int t = 0; t < 4; ++t) sacc[t] = (f32x4){0.f, 0.f, 0.f, 0.f};
#pragma unroll
      for (int t = 0; t < 4; ++t) {
        bf16x8 bk0 = *(const bf16x8*)&Ks[(t * 16 + l16) * 72 + quad * 8];
        bf16x8 bk1 = *(const bf16x8*)&Ks[(t * 16 + l16) * 72 + 32 + quad * 8];
        sacc[t] = __builtin_amdgcn_mfma_f32_16x16x32_bf16(aq[x][0], bk0, sacc[t], 0, 0, 0);
        sacc[t] = __builtin_amdgcn_mfma_f32_16x16x32_bf16(aq[x][1], bk1, sacc[t], 0, 0, 0);
      }

      const bool diag = (kb == nx);
#pragma unroll
      for (int r = 0; r < 4; ++r) {
        int qpos = wid * 16 + quad * 4 + r;
        union { bf16_t bv[4]; uint2 u; } pk;
        float rs = 0.f;
#pragma unroll
        for (int t = 0; t < 4; ++t) {
          float p = __builtin_exp2f(sacc[t][r]);
          if (diag && (t * 16 + l16 > qpos)) p = 0.f;
          rs += p;
          pk.bv[t] = (bf16_t)p;
        }
        lsum[x][r] += rs;
        *(uint2*)&Ps[wid][(quad * 4 + r) * 72 + l16 * 4] = pk.u;   // col' = pi(key)
      }

      bf16x8 pa0 = *(const bf16x8*)&Ps[wid][l16 * 72 + quad * 8];
      bf16x8 pa1 = *(const bf16x8*)&Ps[wid][l16 * 72 + 32 + quad * 8];
#pragma unroll
      for (int t = 0; t < 4; ++t) {
        bf16x8 vb0 = *(const bf16x8*)&Vs[(t * 16 + l16) * 72 + quad * 8];
        bf16x8 vb1 = *(const bf16x8*)&Vs[(t * 16 + l16) * 72 + 32 + quad * 8];
        o_acc[x][t] = __builtin_amdgcn_mfma_f32_16x16x32_bf16(pa0, vb0, o_acc[x][t], 0, 0, 0);
        o_acc[x][t] = __builtin_amdgcn_mfma_f32_16x16x32_bf16(pa1, vb1, o_acc[x][t], 0, 0, 0);
      }
    }
  }

#pragma unroll
  for (int x = 0; x < 2; ++x) {
    float inv[4];
#pragma unroll
    for (int r = 0; r < 4; ++r) {
      float s = lsum[x][r];
#pragma unroll
      for (int off = 1; off < 16; off <<= 1) s += __shfl_xor(s, off);
      inv[r] = 1.f / s;
    }
#pragma unroll
    for (int t = 0; t < 4; ++t)
#pragma unroll
      for (int r = 0; r < 4; ++r) {
        int row = wid * 16 + quad * 4 + r;
        int col = t * 16 + l16;
        o[(rowb[x] + row) * D_ + hoff + col] = (bf16_t)(o_acc[x][t][r] * inv[r]);
      }
  }
}

// ---------------- launch ----------------
extern "C" void kernel_launch(void* const* d_in, const int* in_sizes, int n_in,
                              void* d_out, int out_size, void* d_ws, size_t ws_size,
                              hipStream_t stream) {
  const float* hs = (const float*)d_in[0];
  const int* pos  = (const int*)d_in[1];
  const float* wq = (const float*)d_in[2];
  const float* wk = (const float*)d_in[3];
  const float* wv = (const float*)d_in[4];
  const float* wo = (const float*)d_in[5];

  bf16_t* ws   = (bf16_t*)d_ws;
  bf16_t* hsb  = ws;                          // M_*D_
  bf16_t* wT   = hsb + (size_t)M_ * D_;       // 4*D_*D_
  bf16_t* qkv  = wT + (size_t)4 * D_ * D_;    // 3*M_*D_ (q, k, vt slots)
  bf16_t* attn = qkv + (size_t)3 * M_ * D_;   // M_*D_
  bf16_t* qw  = qkv;
  bf16_t* kw  = qkv + (size_t)M_ * D_;
  bf16_t* vtg = qkv + (size_t)2 * M_ * D_;    // V transposed (written by gemm z=2 epilogue)

  cast_bf16_kernel<<<(M_ * D_ / 4 + 255) / 256, 256, 0, stream>>>(hs, hsb, M_ * D_ / 4);
  transpose_cast_kernel<<<dim3(D_ / 32, D_ / 32, 4), dim3(32, 8), 0, stream>>>(wq, wk, wv, wo, wT);
  gemm128<true><<<dim3(D_ / 128, M_ / 128, 3), 256, 0, stream>>>(hsb, wT, (void*)qkv, vtg, pos);
  attn_kernel<<<dim3(NB_ / 2, H_, B_), 256, 0, stream>>>(qw, kw, vtg, attn);
  gemm128<false><<<dim3(D_ / 128, M_ / 128, 1), 256, 0, stream>>>(attn, wT + (size_t)3 * D_ * D_, d_out, nullptr, pos);
}